// Round 1
// baseline (1193.862 us; speedup 1.0000x reference)
//
#include <hip/hip_runtime.h>

#define N_NODES 81920
#define N_EDGES 1310720
#define NG 256
#define D 64
#define TM 64
#define SA 65   // LDS row stride for A/X tiles: (m*65+k)%32 spreads banks, 2-way max

// ---------------- CSR build ----------------

__global__ void zero_ints(int* __restrict__ p, int n) {
    int i = blockIdx.x * blockDim.x + threadIdx.x;
    if (i < n) p[i] = 0;
}

__global__ void count_deg(const int* __restrict__ dst, int* __restrict__ cnt) {
    int e = blockIdx.x * blockDim.x + threadIdx.x;
    if (e < N_EDGES) atomicAdd(&cnt[dst[e]], 1);
}

__global__ void scan_block(const int* __restrict__ cnt, int* __restrict__ row_ptr,
                           int* __restrict__ bsums) {
    __shared__ int s[256];
    int tid = threadIdx.x;
    int i = blockIdx.x * 256 + tid;
    int v = cnt[i];
    s[tid] = v;
    __syncthreads();
    for (int ofs = 1; ofs < 256; ofs <<= 1) {
        int t = (tid >= ofs) ? s[tid - ofs] : 0;
        __syncthreads();
        s[tid] += t;
        __syncthreads();
    }
    row_ptr[i] = s[tid] - v;               // exclusive
    if (tid == 255) bsums[blockIdx.x] = s[255];
}

__global__ void scan_top(int* __restrict__ bsums) {   // 320 entries, 1 block x 512
    __shared__ int s[512];
    int tid = threadIdx.x;
    int v = (tid < 320) ? bsums[tid] : 0;
    s[tid] = v;
    __syncthreads();
    for (int ofs = 1; ofs < 512; ofs <<= 1) {
        int t = (tid >= ofs) ? s[tid - ofs] : 0;
        __syncthreads();
        s[tid] += t;
        __syncthreads();
    }
    if (tid < 320) bsums[tid] = s[tid] - v; // exclusive
}

__global__ void add_offsets(int* __restrict__ row_ptr, const int* __restrict__ bsums) {
    int i = blockIdx.x * 256 + threadIdx.x;
    row_ptr[i] += bsums[blockIdx.x];
    if (i == 0) row_ptr[N_NODES] = N_EDGES;
}

// pack (src, dst%64) into one int: src < 2^17, 6 bits for dst-in-block
__global__ void bucket(const int* __restrict__ src, const int* __restrict__ dst,
                       const int* __restrict__ row_ptr, int* __restrict__ cur,
                       int* __restrict__ esp) {
    int e = blockIdx.x * blockDim.x + threadIdx.x;
    if (e < N_EDGES) {
        int d = dst[e];
        int ofs = atomicAdd(&cur[d], 1);
        esp[row_ptr[d] + ofs] = (src[e] << 6) | (d & 63);
    }
}

__global__ void find_first(const int* __restrict__ batch, int* __restrict__ fidx) {
    int i = blockIdx.x * blockDim.x + threadIdx.x;
    if (i < N_NODES) {
        int b = batch[i];
        if (i == 0 || batch[i - 1] != b) fidx[b] = i;
    }
}

// ---------------- fused SAGE layer: aggregate (LDS atomics) + dual GEMM ----------------

__global__ __launch_bounds__(256, 3) void sage_layer(
    const float* __restrict__ hin, float* __restrict__ hout,
    const int* __restrict__ row_ptr, const int* __restrict__ esp,
    const float* __restrict__ Wl, const float* __restrict__ bl,
    const float* __restrict__ Wr, int relu)
{
    __shared__ float As[TM * SA];     // mean-aggregated neighbors, [m][k]
    __shared__ float Xs[TM * SA];     // self features
    __shared__ float Wls[D * D];      // Wl staged; Wr read from global (L1, 16 KB)
    __shared__ float bls[D];
    __shared__ float invs[TM];

    const int tid  = threadIdx.x;
    const int base = blockIdx.x * TM;

    for (int i = tid; i < D * D / 4; i += 256)
        ((float4*)Wls)[i] = ((const float4*)Wl)[i];
    if (tid < D) bls[tid] = bl[tid];
    if (tid < TM) {
        int deg = row_ptr[base + tid + 1] - row_ptr[base + tid];
        invs[tid] = 1.0f / (float)max(deg, 1);
    }
    for (int idx = tid; idx < TM * D; idx += 256) {
        int m = idx >> 6, k = idx & 63;
        Xs[m * SA + k] = hin[(base << 6) + idx];
        As[m * SA + k] = 0.0f;
    }
    __syncthreads();

    // edge-parallel aggregation: this block's CSR edge range is contiguous
    const int lane = tid & 63;
    const int w    = tid >> 6;
    const int e0   = row_ptr[base];
    const int e1   = row_ptr[base + TM];
    #pragma unroll 4
    for (int e = e0 + w; e < e1; e += 4) {
        int p = esp[e];                         // wave-uniform broadcast load
        float v = hin[(p >> 6) * D + lane];     // coalesced 256B row gather
        atomicAdd(&As[(p & 63) * SA + lane], v); // ds_add_f32, 2-way bank alias (free)
    }
    __syncthreads();

    for (int idx = tid; idx < TM * D; idx += 256) {
        int m = idx >> 6, k = idx & 63;
        As[m * SA + k] *= invs[m];
    }
    __syncthreads();

    // GEMM: out[m][j] = sum_k As[m][k]*Wl[k][j] + Xs[m][k]*Wr[k][j] + bl[j]
    const int j0 = (tid & 15) << 2;
    const int m0 = (tid >> 4) << 2;
    float o[4][4];
    float4 b4 = *(const float4*)&bls[j0];
    #pragma unroll
    for (int mi = 0; mi < 4; ++mi) {
        o[mi][0] = b4.x; o[mi][1] = b4.y; o[mi][2] = b4.z; o[mi][3] = b4.w;
    }

    #pragma unroll 8
    for (int k = 0; k < D; ++k) {
        float4 wl = *(const float4*)&Wls[(k << 6) + j0];
        float4 wr = *(const float4*)&Wr[(k << 6) + j0];   // global, L1-resident
        #pragma unroll
        for (int mi = 0; mi < 4; ++mi) {
            float a = As[(m0 + mi) * SA + k];
            float x = Xs[(m0 + mi) * SA + k];
            o[mi][0] += a * wl.x + x * wr.x;
            o[mi][1] += a * wl.y + x * wr.y;
            o[mi][2] += a * wl.z + x * wr.z;
            o[mi][3] += a * wl.w + x * wr.w;
        }
    }

    #pragma unroll
    for (int mi = 0; mi < 4; ++mi) {
        float4 r = make_float4(o[mi][0], o[mi][1], o[mi][2], o[mi][3]);
        if (relu) {
            r.x = fmaxf(r.x, 0.f); r.y = fmaxf(r.y, 0.f);
            r.z = fmaxf(r.z, 0.f); r.w = fmaxf(r.w, 0.f);
        }
        *(float4*)&hout[(base + m0 + mi) * D + j0] = r;
    }
}

// ---------------- final layer: only the 256 output nodes ----------------

__global__ void final_agg(const float* __restrict__ hin, const int* __restrict__ row_ptr,
                          const int* __restrict__ esp, const int* __restrict__ fidx,
                          float* __restrict__ aggF, float* __restrict__ xF)
{
    int gw   = (blockIdx.x * blockDim.x + threadIdx.x) >> 6;  // one wave per output node
    int lane = threadIdx.x & 63;
    if (gw >= NG) return;
    int node = fidx[gw];
    int s = row_ptr[node];
    int epd = row_ptr[node + 1];
    float acc = 0.f;
    int e = s;
    for (; e + 4 <= epd; e += 4) {
        int p0 = esp[e], p1 = esp[e + 1], p2 = esp[e + 2], p3 = esp[e + 3];
        float v0 = hin[(p0 >> 6) * D + lane];
        float v1 = hin[(p1 >> 6) * D + lane];
        float v2 = hin[(p2 >> 6) * D + lane];
        float v3 = hin[(p3 >> 6) * D + lane];
        acc += (v0 + v1) + (v2 + v3);
    }
    for (; e < epd; ++e) acc += hin[(esp[e] >> 6) * D + lane];
    acc *= 1.0f / (float)max(epd - s, 1);
    aggF[gw * D + lane] = acc;
    xF[gw * D + lane]   = hin[node * D + lane];
}

__global__ __launch_bounds__(256, 3) void final_gemm(
    const float* __restrict__ aggF, const float* __restrict__ xF,
    const float* __restrict__ Wl, const float* __restrict__ bl,
    const float* __restrict__ Wr, float* __restrict__ out)
{
    __shared__ float As[TM * SA];
    __shared__ float Xs[TM * SA];
    __shared__ float Wls[D * D];
    __shared__ float bls[D];

    const int tid  = threadIdx.x;
    const int base = blockIdx.x * TM;

    for (int i = tid; i < D * D / 4; i += 256)
        ((float4*)Wls)[i] = ((const float4*)Wl)[i];
    if (tid < D) bls[tid] = bl[tid];
    for (int idx = tid; idx < TM * D; idx += 256) {
        int m = idx >> 6, k = idx & 63;
        As[m * SA + k] = aggF[(base << 6) + idx];
        Xs[m * SA + k] = xF[(base << 6) + idx];
    }
    __syncthreads();

    const int j0 = (tid & 15) << 2;
    const int m0 = (tid >> 4) << 2;
    float o[4][4];
    float4 b4 = *(const float4*)&bls[j0];
    #pragma unroll
    for (int mi = 0; mi < 4; ++mi) {
        o[mi][0] = b4.x; o[mi][1] = b4.y; o[mi][2] = b4.z; o[mi][3] = b4.w;
    }
    #pragma unroll 8
    for (int k = 0; k < D; ++k) {
        float4 wl = *(const float4*)&Wls[(k << 6) + j0];
        float4 wr = *(const float4*)&Wr[(k << 6) + j0];
        #pragma unroll
        for (int mi = 0; mi < 4; ++mi) {
            float a = As[(m0 + mi) * SA + k];
            float x = Xs[(m0 + mi) * SA + k];
            o[mi][0] += a * wl.x + x * wr.x;
            o[mi][1] += a * wl.y + x * wr.y;
            o[mi][2] += a * wl.z + x * wr.z;
            o[mi][3] += a * wl.w + x * wr.w;
        }
    }
    #pragma unroll
    for (int mi = 0; mi < 4; ++mi) {
        float4 r = make_float4(o[mi][0], o[mi][1], o[mi][2], o[mi][3]);
        *(float4*)&out[(base + m0 + mi) * D + j0] = r;
    }
}

// ---------------- launch ----------------

extern "C" void kernel_launch(void* const* d_in, const int* in_sizes, int n_in,
                              void* d_out, int out_size, void* d_ws, size_t ws_size,
                              hipStream_t stream)
{
    const float* x     = (const float*)d_in[0];
    const int*   ei    = (const int*)d_in[1];
    const int*   batch = (const int*)d_in[2];
    const float* Wl0 = (const float*)d_in[3];
    const float* bl0 = (const float*)d_in[4];
    const float* Wr0 = (const float*)d_in[5];
    const float* Wl1 = (const float*)d_in[6];
    const float* bl1 = (const float*)d_in[7];
    const float* Wr1 = (const float*)d_in[8];
    const float* Wl2 = (const float*)d_in[9];
    const float* bl2 = (const float*)d_in[10];
    const float* Wr2 = (const float*)d_in[11];
    float* out = (float*)d_out;

    const int* src = ei;             // edge_index[0]
    const int* dst = ei + N_EDGES;   // edge_index[1]

    char* ws = (char*)d_ws;
    size_t off = 0;
    auto alloc = [&](size_t bytes) -> void* {
        void* p = ws + off;
        off = (off + bytes + 255) & ~(size_t)255;
        return p;
    };
    int*   row_ptr = (int*)alloc((N_NODES + 1) * sizeof(int));
    int*   cnt     = (int*)alloc(N_NODES * sizeof(int));       // reused as cursor
    int*   bsums   = (int*)alloc(512 * sizeof(int));
    int*   fidx    = (int*)alloc(NG * sizeof(int));
    float* aggF    = (float*)alloc((size_t)NG * D * sizeof(float));
    float* xF      = (float*)alloc((size_t)NG * D * sizeof(float));
    int*   esp     = (int*)alloc((size_t)N_EDGES * sizeof(int));
    float* h1      = (float*)alloc((size_t)N_NODES * D * sizeof(float));
    float* h2      = (float*)alloc((size_t)N_NODES * D * sizeof(float));
    (void)ws_size; (void)in_sizes; (void)n_in; (void)out_size;

    zero_ints <<<(N_NODES + 255) / 256, 256, 0, stream>>>(cnt, N_NODES);
    count_deg <<<(N_EDGES + 255) / 256, 256, 0, stream>>>(dst, cnt);
    scan_block<<<320, 256, 0, stream>>>(cnt, row_ptr, bsums);
    scan_top  <<<1, 512, 0, stream>>>(bsums);
    add_offsets<<<320, 256, 0, stream>>>(row_ptr, bsums);
    zero_ints <<<(N_NODES + 255) / 256, 256, 0, stream>>>(cnt, N_NODES);
    bucket    <<<(N_EDGES + 255) / 256, 256, 0, stream>>>(src, dst, row_ptr, cnt, esp);
    find_first<<<320, 256, 0, stream>>>(batch, fidx);

    sage_layer<<<N_NODES / TM, 256, 0, stream>>>(x,  h1, row_ptr, esp, Wl0, bl0, Wr0, 1);
    sage_layer<<<N_NODES / TM, 256, 0, stream>>>(h1, h2, row_ptr, esp, Wl1, bl1, Wr1, 1);

    final_agg <<<NG / 4, 256, 0, stream>>>(h2, row_ptr, esp, fidx, aggF, xF);
    final_gemm<<<NG / TM, 256, 0, stream>>>(aggF, xF, Wl2, bl2, Wr2, out);
}

// Round 2
// 1183.065 us; speedup vs baseline: 1.0091x; 1.0091x over previous
//
#include <hip/hip_runtime.h>

#define N_NODES 81920
#define N_EDGES 1310720
#define NG 256
#define D 64
#define TM 64
#define SA 65   // LDS row stride: bank = (m + lane) % 32 -> uniform 2-way alias (free)

// ---------------- CSR build ----------------

__global__ void zero_ints(int* __restrict__ p, int n) {
    int i = blockIdx.x * blockDim.x + threadIdx.x;
    if (i < n) p[i] = 0;
}

__global__ void count_deg(const int* __restrict__ dst, int* __restrict__ cnt) {
    int e = blockIdx.x * blockDim.x + threadIdx.x;
    if (e < N_EDGES) atomicAdd(&cnt[dst[e]], 1);
}

__global__ void scan_block(const int* __restrict__ cnt, int* __restrict__ row_ptr,
                           int* __restrict__ bsums) {
    __shared__ int s[256];
    int tid = threadIdx.x;
    int i = blockIdx.x * 256 + tid;
    int v = cnt[i];
    s[tid] = v;
    __syncthreads();
    for (int ofs = 1; ofs < 256; ofs <<= 1) {
        int t = (tid >= ofs) ? s[tid - ofs] : 0;
        __syncthreads();
        s[tid] += t;
        __syncthreads();
    }
    row_ptr[i] = s[tid] - v;               // exclusive
    if (tid == 255) bsums[blockIdx.x] = s[255];
}

__global__ void scan_top(int* __restrict__ bsums) {   // 320 entries, 1 block x 512
    __shared__ int s[512];
    int tid = threadIdx.x;
    int v = (tid < 320) ? bsums[tid] : 0;
    s[tid] = v;
    __syncthreads();
    for (int ofs = 1; ofs < 512; ofs <<= 1) {
        int t = (tid >= ofs) ? s[tid - ofs] : 0;
        __syncthreads();
        s[tid] += t;
        __syncthreads();
    }
    if (tid < 320) bsums[tid] = s[tid] - v; // exclusive
}

__global__ void add_offsets(int* __restrict__ row_ptr, const int* __restrict__ bsums) {
    int i = blockIdx.x * 256 + threadIdx.x;
    row_ptr[i] += bsums[blockIdx.x];
    if (i == 0) row_ptr[N_NODES] = N_EDGES;
}

// pack (src, dst%64) into one int: src < 2^17, 6 bits for dst-in-block
__global__ void bucket(const int* __restrict__ src, const int* __restrict__ dst,
                       const int* __restrict__ row_ptr, int* __restrict__ cur,
                       int* __restrict__ esp) {
    int e = blockIdx.x * blockDim.x + threadIdx.x;
    if (e < N_EDGES) {
        int d = dst[e];
        int ofs = atomicAdd(&cur[d], 1);
        esp[row_ptr[d] + ofs] = (src[e] << 6) | (d & 63);
    }
}

__global__ void find_first(const int* __restrict__ batch, int* __restrict__ fidx) {
    int i = blockIdx.x * blockDim.x + threadIdx.x;
    if (i < N_NODES) {
        int b = batch[i];
        if (i == 0 || batch[i - 1] != b) fidx[b] = i;
    }
}

// ---------------- fused SAGE layer: aggregate (LDS atomics) + dual GEMM ----------------
// LDS: As + Xs only (~34 KB) -> 4 blocks/CU. Weights read from global (L1-hot).

__global__ __launch_bounds__(256, 4) void sage_layer(
    const float* __restrict__ hin, float* __restrict__ hout,
    const int* __restrict__ row_ptr, const int* __restrict__ esp,
    const float* __restrict__ Wl, const float* __restrict__ bl,
    const float* __restrict__ Wr, int relu)
{
    __shared__ float As[TM * SA];     // mean-aggregated neighbors, [m][k]
    __shared__ float Xs[TM * SA];     // self features
    __shared__ float invs[TM];

    const int tid  = threadIdx.x;
    const int base = blockIdx.x * TM;
    const int lane = tid & 63;
    const int w    = tid >> 6;

    if (tid < TM) {
        int deg = row_ptr[base + tid + 1] - row_ptr[base + tid];
        invs[tid] = 1.0f / (float)max(deg, 1);
    }
    for (int idx = tid; idx < TM * D; idx += 256) {
        int m = idx >> 6, k = idx & 63;
        Xs[m * SA + k] = hin[(base << 6) + idx];
        As[m * SA + k] = 0.0f;
    }
    __syncthreads();

    // edge-parallel aggregation: contiguous chunk per wave, 8-deep batched MLP
    const int e0    = row_ptr[base];
    const int e1    = row_ptr[base + TM];
    const int chunk = ((e1 - e0) + 3) >> 2;
    int e = e0 + w * chunk;
    const int ee = min(e + chunk, e1);

    for (; e + 8 <= ee; e += 8) {
        int p[8];
        float v[8];
        #pragma unroll
        for (int u = 0; u < 8; ++u) p[u] = esp[e + u];        // wave-uniform, L2-hot
        #pragma unroll
        for (int u = 0; u < 8; ++u) v[u] = hin[(p[u] >> 6) * D + lane];  // 8 gathers in flight
        #pragma unroll
        for (int u = 0; u < 8; ++u) atomicAdd(&As[(p[u] & 63) * SA + lane], v[u]);
    }
    for (; e < ee; ++e) {
        int p = esp[e];
        atomicAdd(&As[(p & 63) * SA + lane], hin[(p >> 6) * D + lane]);
    }
    __syncthreads();

    for (int idx = tid; idx < TM * D; idx += 256) {
        int m = idx >> 6, k = idx & 63;
        As[m * SA + k] *= invs[m];
    }
    __syncthreads();

    // GEMM: out[m][j] = sum_k As[m][k]*Wl[k][j] + Xs[m][k]*Wr[k][j] + bl[j]
    const int j0 = (tid & 15) << 2;
    const int m0 = (tid >> 4) << 2;
    float o[4][4];
    float4 b4 = *(const float4*)&bl[j0];
    #pragma unroll
    for (int mi = 0; mi < 4; ++mi) {
        o[mi][0] = b4.x; o[mi][1] = b4.y; o[mi][2] = b4.z; o[mi][3] = b4.w;
    }

    #pragma unroll 8
    for (int k = 0; k < D; ++k) {
        float4 wl = *(const float4*)&Wl[(k << 6) + j0];   // global, L1-resident broadcast
        float4 wr = *(const float4*)&Wr[(k << 6) + j0];
        #pragma unroll
        for (int mi = 0; mi < 4; ++mi) {
            float a = As[(m0 + mi) * SA + k];
            float x = Xs[(m0 + mi) * SA + k];
            o[mi][0] += a * wl.x + x * wr.x;
            o[mi][1] += a * wl.y + x * wr.y;
            o[mi][2] += a * wl.z + x * wr.z;
            o[mi][3] += a * wl.w + x * wr.w;
        }
    }

    #pragma unroll
    for (int mi = 0; mi < 4; ++mi) {
        float4 r = make_float4(o[mi][0], o[mi][1], o[mi][2], o[mi][3]);
        if (relu) {
            r.x = fmaxf(r.x, 0.f); r.y = fmaxf(r.y, 0.f);
            r.z = fmaxf(r.z, 0.f); r.w = fmaxf(r.w, 0.f);
        }
        *(float4*)&hout[(base + m0 + mi) * D + j0] = r;
    }
}

// ---------------- final layer: only the 256 output nodes ----------------

__global__ void final_agg(const float* __restrict__ hin, const int* __restrict__ row_ptr,
                          const int* __restrict__ esp, const int* __restrict__ fidx,
                          float* __restrict__ aggF, float* __restrict__ xF)
{
    int gw   = (blockIdx.x * blockDim.x + threadIdx.x) >> 6;  // one wave per output node
    int lane = threadIdx.x & 63;
    if (gw >= NG) return;
    int node = fidx[gw];
    int s = row_ptr[node];
    int epd = row_ptr[node + 1];
    float acc = 0.f;
    int e = s;
    for (; e + 8 <= epd; e += 8) {
        int p[8];
        float v[8];
        #pragma unroll
        for (int u = 0; u < 8; ++u) p[u] = esp[e + u];
        #pragma unroll
        for (int u = 0; u < 8; ++u) v[u] = hin[(p[u] >> 6) * D + lane];
        #pragma unroll
        for (int u = 0; u < 8; ++u) acc += v[u];
    }
    for (; e < epd; ++e) acc += hin[(esp[e] >> 6) * D + lane];
    acc *= 1.0f / (float)max(epd - s, 1);
    aggF[gw * D + lane] = acc;
    xF[gw * D + lane]   = hin[node * D + lane];
}

__global__ __launch_bounds__(256, 3) void final_gemm(
    const float* __restrict__ aggF, const float* __restrict__ xF,
    const float* __restrict__ Wl, const float* __restrict__ bl,
    const float* __restrict__ Wr, float* __restrict__ out)
{
    __shared__ float As[TM * SA];
    __shared__ float Xs[TM * SA];

    const int tid  = threadIdx.x;
    const int base = blockIdx.x * TM;

    for (int idx = tid; idx < TM * D; idx += 256) {
        int m = idx >> 6, k = idx & 63;
        As[m * SA + k] = aggF[(base << 6) + idx];
        Xs[m * SA + k] = xF[(base << 6) + idx];
    }
    __syncthreads();

    const int j0 = (tid & 15) << 2;
    const int m0 = (tid >> 4) << 2;
    float o[4][4];
    float4 b4 = *(const float4*)&bl[j0];
    #pragma unroll
    for (int mi = 0; mi < 4; ++mi) {
        o[mi][0] = b4.x; o[mi][1] = b4.y; o[mi][2] = b4.z; o[mi][3] = b4.w;
    }
    #pragma unroll 8
    for (int k = 0; k < D; ++k) {
        float4 wl = *(const float4*)&Wl[(k << 6) + j0];
        float4 wr = *(const float4*)&Wr[(k << 6) + j0];
        #pragma unroll
        for (int mi = 0; mi < 4; ++mi) {
            float a = As[(m0 + mi) * SA + k];
            float x = Xs[(m0 + mi) * SA + k];
            o[mi][0] += a * wl.x + x * wr.x;
            o[mi][1] += a * wl.y + x * wr.y;
            o[mi][2] += a * wl.z + x * wr.z;
            o[mi][3] += a * wl.w + x * wr.w;
        }
    }
    #pragma unroll
    for (int mi = 0; mi < 4; ++mi) {
        float4 r = make_float4(o[mi][0], o[mi][1], o[mi][2], o[mi][3]);
        *(float4*)&out[(base + m0 + mi) * D + j0] = r;
    }
}

// ---------------- launch ----------------

extern "C" void kernel_launch(void* const* d_in, const int* in_sizes, int n_in,
                              void* d_out, int out_size, void* d_ws, size_t ws_size,
                              hipStream_t stream)
{
    const float* x     = (const float*)d_in[0];
    const int*   ei    = (const int*)d_in[1];
    const int*   batch = (const int*)d_in[2];
    const float* Wl0 = (const float*)d_in[3];
    const float* bl0 = (const float*)d_in[4];
    const float* Wr0 = (const float*)d_in[5];
    const float* Wl1 = (const float*)d_in[6];
    const float* bl1 = (const float*)d_in[7];
    const float* Wr1 = (const float*)d_in[8];
    const float* Wl2 = (const float*)d_in[9];
    const float* bl2 = (const float*)d_in[10];
    const float* Wr2 = (const float*)d_in[11];
    float* out = (float*)d_out;

    const int* src = ei;             // edge_index[0]
    const int* dst = ei + N_EDGES;   // edge_index[1]

    char* ws = (char*)d_ws;
    size_t off = 0;
    auto alloc = [&](size_t bytes) -> void* {
        void* p = ws + off;
        off = (off + bytes + 255) & ~(size_t)255;
        return p;
    };
    int*   row_ptr = (int*)alloc((N_NODES + 1) * sizeof(int));
    int*   cnt     = (int*)alloc(N_NODES * sizeof(int));       // reused as cursor
    int*   bsums   = (int*)alloc(512 * sizeof(int));
    int*   fidx    = (int*)alloc(NG * sizeof(int));
    float* aggF    = (float*)alloc((size_t)NG * D * sizeof(float));
    float* xF      = (float*)alloc((size_t)NG * D * sizeof(float));
    int*   esp     = (int*)alloc((size_t)N_EDGES * sizeof(int));
    float* h1      = (float*)alloc((size_t)N_NODES * D * sizeof(float));
    float* h2      = (float*)alloc((size_t)N_NODES * D * sizeof(float));
    (void)ws_size; (void)in_sizes; (void)n_in; (void)out_size;

    zero_ints <<<(N_NODES + 255) / 256, 256, 0, stream>>>(cnt, N_NODES);
    count_deg <<<(N_EDGES + 255) / 256, 256, 0, stream>>>(dst, cnt);
    scan_block<<<320, 256, 0, stream>>>(cnt, row_ptr, bsums);
    scan_top  <<<1, 512, 0, stream>>>(bsums);
    add_offsets<<<320, 256, 0, stream>>>(row_ptr, bsums);
    zero_ints <<<(N_NODES + 255) / 256, 256, 0, stream>>>(cnt, N_NODES);
    bucket    <<<(N_EDGES + 255) / 256, 256, 0, stream>>>(src, dst, row_ptr, cnt, esp);
    find_first<<<320, 256, 0, stream>>>(batch, fidx);

    sage_layer<<<N_NODES / TM, 256, 0, stream>>>(x,  h1, row_ptr, esp, Wl0, bl0, Wr0, 1);
    sage_layer<<<N_NODES / TM, 256, 0, stream>>>(h1, h2, row_ptr, esp, Wl1, bl1, Wr1, 1);

    final_agg <<<NG / 4, 256, 0, stream>>>(h2, row_ptr, esp, fidx, aggF, xF);
    final_gemm<<<NG / TM, 256, 0, stream>>>(aggF, xF, Wl2, bl2, Wr2, out);
}